// Round 17
// baseline (185.266 us; speedup 1.0000x reference)
//
#include <hip/hip_runtime.h>

#define N_ 100000
#define E_ 600000
#define IND_ 128
#define OUTD_ 256
#define NT_ (N_/16)        // 6250 row-tiles of 16
#define NB_ 98             // scan blocks of 1024
#define CASTN_ (N_*IND_/2) // 6.4M u32 words of bf16 pairs
#define CAST4_ (CASTN_/2)  // 3.2M float4 -> u32x2 units

typedef __attribute__((ext_vector_type(8))) short bf16x8;
typedef __attribute__((ext_vector_type(4))) float f32x4;
typedef __attribute__((ext_vector_type(2))) unsigned int u32x2;

static __device__ __forceinline__ unsigned f2bf_u(float f){
  union { float f; unsigned u; } v; v.f = f;
  return (v.u + 0x7fffu + ((v.u >> 16) & 1u)) >> 16;   // RNE bf16
}
static __device__ __forceinline__ unsigned pack2(float a, float b){
  return f2bf_u(a) | (f2bf_u(b) << 16);
}
static __device__ __forceinline__ float blo(unsigned u){
  union { unsigned u; float f; } v; v.u = u << 16; return v.f;
}
static __device__ __forceinline__ float bhi(unsigned u){
  union { unsigned u; float f; } v; v.u = u & 0xffff0000u; return v.f;
}
// async global->LDS DMA, 16B per lane per call (wave: 1KB). LDS base must be wave-uniform.
static __device__ __forceinline__ void gload_lds16(const bf16x8* g, bf16x8* l){
  __builtin_amdgcn_global_load_lds((const __attribute__((address_space(1))) void*)g,
                                   (__attribute__((address_space(3))) void*)l, 16, 0, 0);
}

// ---- weight prep (fp32 -> bf16 fragment order) + BN fold + x -> bf16 cast + degree count
__global__ void k_prep(const float* __restrict__ x,
                       const float* __restrict__ W1, const float* __restrict__ W2,
                       const float* __restrict__ Wp, const float* __restrict__ b2,
                       const float* __restrict__ gamma, const float* __restrict__ beta,
                       const float* __restrict__ mean, const float* __restrict__ var,
                       const float* __restrict__ bp,
                       const int* __restrict__ dst, int* __restrict__ deg,
                       unsigned short* __restrict__ W1s, unsigned short* __restrict__ W2s,
                       unsigned short* __restrict__ Wps,
                       float* __restrict__ scale, float* __restrict__ shift,
                       unsigned* __restrict__ xbw)
{
  int gid = blockIdx.x*256 + threadIdx.x;
  if (gid < 16384) {
    const float* W; unsigned short* Ws; int u;
    if (gid < 4096)       { W = W1; Ws = W1s; u = gid; }
    else if (gid < 12288) { W = W2; Ws = W2s; u = gid - 4096; }
    else                  { W = Wp; Ws = Wps; u = gid - 12288; }
    int l  = u & 63;
    int km = (u >> 6) & 1;
    int t  = (u >> 7) & 15;
    int q  = u >> 11;
    int kk = 2*q + km;
    int kb = kk*32 + (l >> 4)*8;
    int c  = 16*t + (l & 15);
    #pragma unroll
    for (int j = 0; j < 8; j++)
      Ws[u*8 + j] = (unsigned short)f2bf_u(W[(size_t)(kb + j)*OUTD_ + c]);
  } else if (gid < 16640) {
    int c = gid - 16384;
    float s = gamma[c] * rsqrtf(var[c] + 1e-5f);
    scale[c] = s;
    shift[c] = (b2[c] - mean[c]) * s + beta[c] + bp[c];
  } else if (gid < 16640 + CAST4_) {
    int ci = gid - 16640;
    float4 v = ((const float4*)x)[ci];
    u32x2 o; o.x = pack2(v.x, v.y); o.y = pack2(v.z, v.w);
    ((u32x2*)xbw)[ci] = o;
  } else if (gid < 16640 + CAST4_ + E_) {
    int e = gid - 16640 - CAST4_;
    atomicAdd(&deg[dst[e]], 1);
  }
}

// merged hierarchical scan: block b sums all preceding (full) 1024-chunks, then scans its own
__global__ __launch_bounds__(1024) void k_scan(const int* __restrict__ deg, int* __restrict__ offs){
  __shared__ int red[16];
  __shared__ int d1[1024];
  int tid = threadIdx.x, b = blockIdx.x;
  // 1) prefix over preceding chunks (all full: b*1024 <= 97*1024 < N_)
  int s = 0;
  for (int base = 0; base < b*1024; base += 1024)
    s += deg[base + tid];
  #pragma unroll
  for (int d = 32; d; d >>= 1) s += __shfl_down(s, d);
  if ((tid & 63) == 0) red[tid >> 6] = s;
  __syncthreads();
  if (tid < 16) {
    int t = red[tid];
    #pragma unroll
    for (int d = 8; d; d >>= 1) t += __shfl_down(t, d, 16);
    if (tid == 0) red[0] = t;
  }
  __syncthreads();
  int bprefix = red[0];
  // 2) own-chunk exclusive scan
  int i = b*1024 + tid;
  int v = (i < N_) ? deg[i] : 0;
  d1[tid] = v;
  __syncthreads();
  #pragma unroll
  for (int d = 1; d < 1024; d <<= 1){
    int t = (tid >= d) ? d1[tid - d] : 0;
    __syncthreads();
    d1[tid] += t;
    __syncthreads();
  }
  if (i < N_) offs[i] = bprefix + d1[tid] - v;
  if (b == 0 && tid == 0) offs[N_] = E_;
}

__global__ void k_fill(const int* __restrict__ src, const int* __restrict__ dst,
                       const int* __restrict__ offs, int* __restrict__ cur, int* __restrict__ adj){
  int e = blockIdx.x*256 + threadIdx.x;
  if (e < E_) {
    int d = dst[e];
    int p = atomicAdd(&cur[d], 1);
    adj[offs[d] + p] = src[e];
  }
}

// one wave per TWO adjacent dst rows (contiguous CSR range, avg 12 edges): flat graded
// unroll 8/4/2/1 over the combined list; per-element row assignment is wave-uniform.
__global__ void k_agg(const unsigned* __restrict__ xb32, const int* __restrict__ offs,
                      const int* __restrict__ adj, const float* __restrict__ epsp,
                      unsigned* __restrict__ h0)
{
  int pair = blockIdx.x*4 + (threadIdx.x >> 6);
  int lane = threadIdx.x & 63;
  int row0 = pair*2;
  if (row0 >= N_) return;
  int b0 = offs[row0], e0 = offs[row0+1], e1 = offs[row0+2];
  int d0 = e0 - b0;
  int total = e1 - b0;
  float a0x0=0,a0y0=0,a0x1=0,a0y1=0,a0x2=0,a0y2=0,a0x3=0,a0y3=0;
  float a1x0=0,a1y0=0,a1x1=0,a1y1=0,a1x2=0,a1y2=0,a1x3=0,a1y3=0;

#define ACC(P, V, S)                                                        \
  { if ((P) < d0) { a0x##S += blo(V); a0y##S += bhi(V); }                   \
    else          { a1x##S += blo(V); a1y##S += bhi(V); } }

  for (int base = 0; base < total; base += 64){
    int cnt = min(64, total - base);
    int idx = adj[b0 + base + min(lane, cnt - 1)];
    int j = 0;
    for (; j + 8 <= cnt; j += 8){
      int n0=__shfl(idx,j+0), n1=__shfl(idx,j+1), n2=__shfl(idx,j+2), n3=__shfl(idx,j+3);
      int n4=__shfl(idx,j+4), n5=__shfl(idx,j+5), n6=__shfl(idx,j+6), n7=__shfl(idx,j+7);
      unsigned v0 = xb32[(size_t)n0*64 + lane];
      unsigned v1 = xb32[(size_t)n1*64 + lane];
      unsigned v2 = xb32[(size_t)n2*64 + lane];
      unsigned v3 = xb32[(size_t)n3*64 + lane];
      unsigned v4 = xb32[(size_t)n4*64 + lane];
      unsigned v5 = xb32[(size_t)n5*64 + lane];
      unsigned v6 = xb32[(size_t)n6*64 + lane];
      unsigned v7 = xb32[(size_t)n7*64 + lane];
      ACC(base+j+0, v0, 0) ACC(base+j+1, v1, 1) ACC(base+j+2, v2, 2) ACC(base+j+3, v3, 3)
      ACC(base+j+4, v4, 0) ACC(base+j+5, v5, 1) ACC(base+j+6, v6, 2) ACC(base+j+7, v7, 3)
    }
    for (; j + 4 <= cnt; j += 4){
      int n0=__shfl(idx,j+0), n1=__shfl(idx,j+1), n2=__shfl(idx,j+2), n3=__shfl(idx,j+3);
      unsigned v0 = xb32[(size_t)n0*64 + lane];
      unsigned v1 = xb32[(size_t)n1*64 + lane];
      unsigned v2 = xb32[(size_t)n2*64 + lane];
      unsigned v3 = xb32[(size_t)n3*64 + lane];
      ACC(base+j+0, v0, 0) ACC(base+j+1, v1, 1) ACC(base+j+2, v2, 2) ACC(base+j+3, v3, 3)
    }
    if (j + 2 <= cnt){
      int n0=__shfl(idx,j+0), n1=__shfl(idx,j+1);
      unsigned v0 = xb32[(size_t)n0*64 + lane];
      unsigned v1 = xb32[(size_t)n1*64 + lane];
      ACC(base+j+0, v0, 0) ACC(base+j+1, v1, 1)
      j += 2;
    }
    if (j < cnt){
      int n = __shfl(idx, j);
      unsigned v = xb32[(size_t)n*64 + lane];
      ACC(base+j, v, 2)
    }
  }
#undef ACC

  float k1 = 1.f + epsp[0];
  unsigned xw0 = xb32[(size_t)row0*64 + lane];
  unsigned xw1 = xb32[(size_t)(row0+1)*64 + lane];
  float a0x = (a0x0 + a0x1) + (a0x2 + a0x3);
  float a0y = (a0y0 + a0y1) + (a0y2 + a0y3);
  float a1x = (a1x0 + a1x1) + (a1x2 + a1x3);
  float a1y = (a1y0 + a1y1) + (a1y2 + a1y3);
  h0[(size_t)row0*64 + lane]     = pack2(fmaf(k1, blo(xw0), a0x), fmaf(k1, bhi(xw0), a0y));
  h0[(size_t)(row0+1)*64 + lane] = pack2(fmaf(k1, blo(xw1), a1x), fmaf(k1, bhi(xw1), a1y));
}

// Fused MLP, T4 pipeline (R13 schedule) with TWO tiles per wave: 32 output rows/wave,
// 32 MFMA per phase per wave. 16 phases of 16KB slices, quad-buffered, vmcnt(8) steady.
// (setprio removed: m190 shows it hurts lockstep barrier-synced GEMM schedules)
__global__ __launch_bounds__(256, 2) void k_mlp(const unsigned short* __restrict__ h0,
        const unsigned short* __restrict__ xb16,
        const bf16x8* __restrict__ W1s, const float* __restrict__ b1,
        const bf16x8* __restrict__ W2s, const bf16x8* __restrict__ Wps,
        const float* __restrict__ scale, const float* __restrict__ shift,
        float* __restrict__ out)
{
  __shared__ bf16x8 w[4][1024];                    // 4 x 16KB weight slices
  __shared__ __align__(16) char trans[4][2][1280]; // per-wave 16x(64B+16B pad)
  int tid = threadIdx.x;
  int wv = tid >> 6, lane = tid & 63, g = lane >> 4, r = lane & 15;
  int tA0 = blockIdx.x*8 + wv*2;
  int tB0 = tA0 + 1;
  int tA = min(tA0, NT_ - 1);
  int tB = min(tB0, NT_ - 1);

  const bf16x8* hrowA = (const bf16x8*)(h0 + ((size_t)tA*16 + r)*IND_);
  const bf16x8* hrowB = (const bf16x8*)(h0 + ((size_t)tB*16 + r)*IND_);
  bf16x8 BA[4], BB[4];
  #pragma unroll
  for (int kk = 0; kk < 4; kk++) BA[kk] = hrowA[kk*4 + g];
  #pragma unroll
  for (int kk = 0; kk < 4; kk++) BB[kk] = hrowB[kk*4 + g];

  // 16 slices of 1024 units (16KB): W1 0..3, W2 4..11, Wp 12..15
  const bf16x8* sl[16];
  #pragma unroll
  for (int i = 0; i < 4; i++)  sl[i]      = W1s + i*1024;
  #pragma unroll
  for (int i = 0; i < 8; i++)  sl[4 + i]  = W2s + i*1024;
  #pragma unroll
  for (int i = 0; i < 4; i++)  sl[12 + i] = Wps + i*1024;

  auto STAGE = [&](int buf, const bf16x8* src){
    #pragma unroll
    for (int i = 0; i < 4; i++)
      gload_lds16(&src[i*256 + wv*64 + lane], &w[buf][i*256 + wv*64]);
  };
  f32x4 accA[16], accB[16];
  auto MF16 = [&](int buf, bf16x8 f0, bf16x8 f1, int tb, f32x4 (&acc)[16]){
    #pragma unroll
    for (int tt = 0; tt < 8; tt++)
      acc[tb+tt] = __builtin_amdgcn_mfma_f32_16x16x32_bf16(w[buf][(tt*2+0)*64 + lane], f0, acc[tb+tt], 0,0,0);
    #pragma unroll
    for (int tt = 0; tt < 8; tt++)
      acc[tb+tt] = __builtin_amdgcn_mfma_f32_16x16x32_bf16(w[buf][(tt*2+1)*64 + lane], f1, acc[tb+tt], 0,0,0);
  };
  #pragma unroll
  for (int t = 0; t < 16; t++){ accA[t] = (f32x4){0.f,0.f,0.f,0.f}; accB[t] = (f32x4){0.f,0.f,0.f,0.f}; }

  const float4* b1v = (const float4*)b1;
  auto EPI = [&](f32x4 (&acc)[16], bf16x8 (&H)[8]){
    #pragma unroll
    for (int kkh = 0; kkh < 8; kkh++){
      char* tr = &trans[wv][kkh & 1][0];
      #pragma unroll
      for (int h = 0; h < 2; h++){
        int t = 2*kkh + h;
        float4 bb = b1v[t*4 + g];
        f32x4 a = acc[t];
        float v0 = fmaxf(a.x + bb.x, 0.f);
        float v1 = fmaxf(a.y + bb.y, 0.f);
        float v2 = fmaxf(a.z + bb.z, 0.f);
        float v3 = fmaxf(a.w + bb.w, 0.f);
        u32x2 dd; dd.x = pack2(v0, v1); dd.y = pack2(v2, v3);
        *(u32x2*)(tr + r*80 + h*32 + g*8) = dd;
      }
      H[kkh] = *(const bf16x8*)(tr + r*80 + g*16);
    }
    #pragma unroll
    for (int t = 0; t < 16; t++) acc[t] = (f32x4){0.f,0.f,0.f,0.f};
  };

#define PHASE(P, VM, FA0, FA1, FB0, FB1, TB)                       \
  { if ((P) + 2 < 16) STAGE(((P)+2)&3, sl[(P)+2]);                 \
    asm volatile("s_waitcnt vmcnt(" VM ")" ::: "memory");          \
    __builtin_amdgcn_s_barrier();                                  \
    MF16((P)&3, FA0, FA1, TB, accA);                               \
    MF16((P)&3, FB0, FB1, TB, accB); }

  STAGE(0, sl[0]);
  STAGE(1, sl[1]);

  // W1: h0 @ W1  (phases 0..3)
  PHASE(0,  "8", BA[0], BA[1], BB[0], BB[1], 0)
  PHASE(1,  "8", BA[0], BA[1], BB[0], BB[1], 8)
  PHASE(2,  "8", BA[2], BA[3], BB[2], BB[3], 0)
  PHASE(3,  "8", BA[2], BA[3], BB[2], BB[3], 8)

  // epilogue B (both tiles): bias+relu -> bf16 H-fragments; runs while slices 4,5 stage
  bf16x8 HA[8], HB[8];
  EPI(accA, HA);
  EPI(accB, HB);

  // W2: h1 @ W2  (phases 4..11)
  PHASE(4,  "8", HA[0], HA[1], HB[0], HB[1], 0)
  PHASE(5,  "8", HA[0], HA[1], HB[0], HB[1], 8)
  PHASE(6,  "8", HA[2], HA[3], HB[2], HB[3], 0)
  PHASE(7,  "8", HA[2], HA[3], HB[2], HB[3], 8)
  PHASE(8,  "8", HA[4], HA[5], HB[4], HB[5], 0)
  PHASE(9,  "8", HA[4], HA[5], HB[4], HB[5], 8)

  // x fragments for the Wp phases (loaded late: B regs dead, most of H dead soon)
  const bf16x8* xrowA = (const bf16x8*)(xb16 + ((size_t)tA*16 + r)*IND_);
  const bf16x8* xrowB = (const bf16x8*)(xb16 + ((size_t)tB*16 + r)*IND_);
  bf16x8 XA[4], XB[4];
  #pragma unroll
  for (int kk = 0; kk < 4; kk++) XA[kk] = xrowA[kk*4 + g];
  #pragma unroll
  for (int kk = 0; kk < 4; kk++) XB[kk] = xrowB[kk*4 + g];

  PHASE(10, "8", HA[6], HA[7], HB[6], HB[7], 0)
  PHASE(11, "8", HA[6], HA[7], HB[6], HB[7], 8)
  // Wp: x @ Wp  (phases 12..15)
  PHASE(12, "8", XA[0], XA[1], XB[0], XB[1], 0)
  PHASE(13, "8", XA[0], XA[1], XB[0], XB[1], 8)
  PHASE(14, "4", XA[2], XA[3], XB[2], XB[3], 0)
  PHASE(15, "0", XA[2], XA[3], XB[2], XB[3], 8)
#undef PHASE

  const float4* sc = (const float4*)scale;
  const float4* sh = (const float4*)shift;
  if (tA0 < NT_){
    #pragma unroll
    for (int t = 0; t < 16; t++){
      float4 s = sc[t*4 + g], b = sh[t*4 + g];
      f32x4 a = accA[t];
      float4 o;
      o.x = fmaf(a.x, s.x, b.x);
      o.y = fmaf(a.y, s.y, b.y);
      o.z = fmaf(a.z, s.z, b.z);
      o.w = fmaf(a.w, s.w, b.w);
      *(float4*)(out + ((size_t)tA*16 + r)*OUTD_ + t*16 + g*4) = o;
    }
  }
  if (tB0 < NT_){
    #pragma unroll
    for (int t = 0; t < 16; t++){
      float4 s = sc[t*4 + g], b = sh[t*4 + g];
      f32x4 a = accB[t];
      float4 o;
      o.x = fmaf(a.x, s.x, b.x);
      o.y = fmaf(a.y, s.y, b.y);
      o.z = fmaf(a.z, s.z, b.z);
      o.w = fmaf(a.w, s.w, b.w);
      *(float4*)(out + ((size_t)tB*16 + r)*OUTD_ + t*16 + g*4) = o;
    }
  }
}

extern "C" void kernel_launch(void* const* d_in, const int* in_sizes, int n_in,
                              void* d_out, int out_size, void* d_ws, size_t ws_size,
                              hipStream_t stream)
{
  const float* x     = (const float*)d_in[0];
  const int*   ei    = (const int*)d_in[1];     // [2][E]: src then dst
  const float* eps   = (const float*)d_in[2];
  const float* W1    = (const float*)d_in[3];
  const float* b1    = (const float*)d_in[4];
  const float* W2    = (const float*)d_in[5];
  const float* b2    = (const float*)d_in[6];
  const float* gamma = (const float*)d_in[7];
  const float* beta  = (const float*)d_in[8];
  const float* rmean = (const float*)d_in[9];
  const float* rvar  = (const float*)d_in[10];
  const float* Wp    = (const float*)d_in[11];
  const float* bp    = (const float*)d_in[12];
  float* out = (float*)d_out;

  char* ws = (char*)d_ws; size_t off = 0;
  auto carve = [&](size_t b)->char* { char* p = ws + off; off = (off + b + 255) & ~(size_t)255; return p; };
  unsigned*       xbuf  = (unsigned*)carve((size_t)CASTN_*4);   // x as bf16 pairs
  unsigned*       h0    = (unsigned*)carve((size_t)N_*64*4);    // h0 as bf16 pairs
  unsigned short* W1s   = (unsigned short*)carve(4096*16);
  unsigned short* W2s   = (unsigned short*)carve(8192*16);
  unsigned short* Wps   = (unsigned short*)carve(4096*16);
  float*          scale = (float*)carve(256*4);
  float*          shift = (float*)carve(256*4);
  int*            deg   = (int*)carve((size_t)N_*4);            // deg, cur adjacent: one memset
  int*            cur   = (int*)carve((size_t)N_*4);
  int*            offs  = (int*)carve((size_t)(N_+1)*4);
  int*            adj   = (int*)carve((size_t)E_*4);

  // deg block is padded to 256B; cur follows immediately -> zero both in one node
  size_t degpad = (((size_t)N_*4 + 255) & ~(size_t)255);
  hipMemsetAsync(deg, 0, degpad + (size_t)N_*4, stream);

  k_prep <<<(16640 + CAST4_ + E_ + 255)/256, 256, 0, stream>>>(x, W1, W2, Wp, b2, gamma, beta,
                                  rmean, rvar, bp, ei + E_, deg,
                                  W1s, W2s, Wps, scale, shift, xbuf);
  k_scan <<<NB_, 1024, 0, stream>>>(deg, offs);
  k_fill <<<(E_+255)/256, 256, 0, stream>>>(ei, ei + E_, offs, cur, adj);
  k_agg  <<<(N_/2+3)/4, 256, 0, stream>>>(xbuf, offs, adj, eps, h0);
  k_mlp  <<<(NT_+7)/8, 256, 0, stream>>>((const unsigned short*)h0, (const unsigned short*)xbuf,
                                         (const bf16x8*)W1s, b1, (const bf16x8*)W2s,
                                         (const bf16x8*)Wps, scale, shift, out);
}

// Round 18
// 174.724 us; speedup vs baseline: 1.0603x; 1.0603x over previous
//
#include <hip/hip_runtime.h>

#define N_ 100000
#define E_ 600000
#define IND_ 128
#define OUTD_ 256
#define NT_ (N_/16)        // 6250 row-tiles of 16
#define NB_ 98             // scan blocks of 1024
#define CASTN_ (N_*IND_/2) // 6.4M u32 words of bf16 pairs
#define CAST4_ (CASTN_/2)  // 3.2M float4 -> u32x2 units

typedef __attribute__((ext_vector_type(8))) short bf16x8;
typedef __attribute__((ext_vector_type(4))) float f32x4;
typedef __attribute__((ext_vector_type(2))) unsigned int u32x2;

static __device__ __forceinline__ unsigned f2bf_u(float f){
  union { float f; unsigned u; } v; v.f = f;
  return (v.u + 0x7fffu + ((v.u >> 16) & 1u)) >> 16;   // RNE bf16
}
static __device__ __forceinline__ unsigned pack2(float a, float b){
  return f2bf_u(a) | (f2bf_u(b) << 16);
}
static __device__ __forceinline__ float blo(unsigned u){
  union { unsigned u; float f; } v; v.u = u << 16; return v.f;
}
static __device__ __forceinline__ float bhi(unsigned u){
  union { unsigned u; float f; } v; v.u = u & 0xffff0000u; return v.f;
}
// async global->LDS DMA, 16B per lane per call (wave: 1KB). LDS base must be wave-uniform.
static __device__ __forceinline__ void gload_lds16(const bf16x8* g, bf16x8* l){
  __builtin_amdgcn_global_load_lds((const __attribute__((address_space(1))) void*)g,
                                   (__attribute__((address_space(3))) void*)l, 16, 0, 0);
}

// ---- weight prep (fp32 -> bf16 fragment order) + BN fold + x -> bf16 cast + degree count
__global__ void k_prep(const float* __restrict__ x,
                       const float* __restrict__ W1, const float* __restrict__ W2,
                       const float* __restrict__ Wp, const float* __restrict__ b2,
                       const float* __restrict__ gamma, const float* __restrict__ beta,
                       const float* __restrict__ mean, const float* __restrict__ var,
                       const float* __restrict__ bp,
                       const int* __restrict__ dst, int* __restrict__ deg,
                       unsigned short* __restrict__ W1s, unsigned short* __restrict__ W2s,
                       unsigned short* __restrict__ Wps,
                       float* __restrict__ scale, float* __restrict__ shift,
                       unsigned* __restrict__ xbw)
{
  int gid = blockIdx.x*256 + threadIdx.x;
  if (gid < 16384) {
    const float* W; unsigned short* Ws; int u;
    if (gid < 4096)       { W = W1; Ws = W1s; u = gid; }
    else if (gid < 12288) { W = W2; Ws = W2s; u = gid - 4096; }
    else                  { W = Wp; Ws = Wps; u = gid - 12288; }
    int l  = u & 63;
    int km = (u >> 6) & 1;
    int t  = (u >> 7) & 15;
    int q  = u >> 11;
    int kk = 2*q + km;
    int kb = kk*32 + (l >> 4)*8;
    int c  = 16*t + (l & 15);
    #pragma unroll
    for (int j = 0; j < 8; j++)
      Ws[u*8 + j] = (unsigned short)f2bf_u(W[(size_t)(kb + j)*OUTD_ + c]);
  } else if (gid < 16640) {
    int c = gid - 16384;
    float s = gamma[c] * rsqrtf(var[c] + 1e-5f);
    scale[c] = s;
    shift[c] = (b2[c] - mean[c]) * s + beta[c] + bp[c];
  } else if (gid < 16640 + CAST4_) {
    int ci = gid - 16640;
    float4 v = ((const float4*)x)[ci];
    u32x2 o; o.x = pack2(v.x, v.y); o.y = pack2(v.z, v.w);
    ((u32x2*)xbw)[ci] = o;
  } else if (gid < 16640 + CAST4_ + E_) {
    int e = gid - 16640 - CAST4_;
    atomicAdd(&deg[dst[e]], 1);
  }
}

// hierarchical scan pass 1: per-1024-chunk sums (parallel, coalesced)
__global__ __launch_bounds__(1024) void k_scan1(const int* __restrict__ deg,
                                                int* __restrict__ bsum, int* __restrict__ offs){
  __shared__ int red[16];
  int tid = threadIdx.x;
  int i = blockIdx.x*1024 + tid;
  int v = (i < N_) ? deg[i] : 0;
  #pragma unroll
  for (int d = 32; d; d >>= 1) v += __shfl_down(v, d);
  if ((tid & 63) == 0) red[tid >> 6] = v;
  __syncthreads();
  if (tid < 16) {
    int s = red[tid];
    #pragma unroll
    for (int d = 8; d; d >>= 1) s += __shfl_down(s, d, 16);
    if (tid == 0) bsum[blockIdx.x] = s;
  }
  if (blockIdx.x == 0 && tid == 0) offs[N_] = E_;
}

// pass 2: each block redundantly scans the 98 block sums + its own chunk
__global__ __launch_bounds__(1024) void k_scan2(const int* __restrict__ deg,
                                                const int* __restrict__ bsum, int* __restrict__ offs){
  __shared__ int bs[128];
  __shared__ int d1[1024];
  int tid = threadIdx.x;
  if (tid < 128) bs[tid] = (tid < NB_) ? bsum[tid] : 0;
  __syncthreads();
  #pragma unroll
  for (int d = 1; d < 128; d <<= 1){
    int v = (tid < 128 && tid >= d) ? bs[tid - d] : 0;
    __syncthreads();
    if (tid < 128) bs[tid] += v;
    __syncthreads();
  }
  int bprefix = (blockIdx.x > 0) ? bs[blockIdx.x - 1] : 0;
  int i = blockIdx.x*1024 + tid;
  int v = (i < N_) ? deg[i] : 0;
  d1[tid] = v;
  __syncthreads();
  #pragma unroll
  for (int d = 1; d < 1024; d <<= 1){
    int t = (tid >= d) ? d1[tid - d] : 0;
    __syncthreads();
    d1[tid] += t;
    __syncthreads();
  }
  if (i < N_) offs[i] = bprefix + d1[tid] - v;
}

__global__ void k_fill(const int* __restrict__ src, const int* __restrict__ dst,
                       const int* __restrict__ offs, int* __restrict__ cur, int* __restrict__ adj){
  int e = blockIdx.x*256 + threadIdx.x;
  if (e < E_) {
    int d = dst[e];
    int p = atomicAdd(&cur[d], 1);
    adj[offs[d] + p] = src[e];
  }
}

// one wave per TWO adjacent dst rows (contiguous CSR range, avg 12 edges): flat graded
// unroll 8/4/2/1 over the combined list; per-element row assignment is wave-uniform.
__global__ void k_agg(const unsigned* __restrict__ xb32, const int* __restrict__ offs,
                      const int* __restrict__ adj, const float* __restrict__ epsp,
                      unsigned* __restrict__ h0)
{
  int pair = blockIdx.x*4 + (threadIdx.x >> 6);
  int lane = threadIdx.x & 63;
  int row0 = pair*2;
  if (row0 >= N_) return;
  int b0 = offs[row0], e0 = offs[row0+1], e1 = offs[row0+2];
  int d0 = e0 - b0;
  int total = e1 - b0;
  float a0x0=0,a0y0=0,a0x1=0,a0y1=0,a0x2=0,a0y2=0,a0x3=0,a0y3=0;
  float a1x0=0,a1y0=0,a1x1=0,a1y1=0,a1x2=0,a1y2=0,a1x3=0,a1y3=0;

#define ACC(P, V, S)                                                        \
  { if ((P) < d0) { a0x##S += blo(V); a0y##S += bhi(V); }                   \
    else          { a1x##S += blo(V); a1y##S += bhi(V); } }

  for (int base = 0; base < total; base += 64){
    int cnt = min(64, total - base);
    int idx = adj[b0 + base + min(lane, cnt - 1)];
    int j = 0;
    for (; j + 8 <= cnt; j += 8){
      int n0=__shfl(idx,j+0), n1=__shfl(idx,j+1), n2=__shfl(idx,j+2), n3=__shfl(idx,j+3);
      int n4=__shfl(idx,j+4), n5=__shfl(idx,j+5), n6=__shfl(idx,j+6), n7=__shfl(idx,j+7);
      unsigned v0 = xb32[(size_t)n0*64 + lane];
      unsigned v1 = xb32[(size_t)n1*64 + lane];
      unsigned v2 = xb32[(size_t)n2*64 + lane];
      unsigned v3 = xb32[(size_t)n3*64 + lane];
      unsigned v4 = xb32[(size_t)n4*64 + lane];
      unsigned v5 = xb32[(size_t)n5*64 + lane];
      unsigned v6 = xb32[(size_t)n6*64 + lane];
      unsigned v7 = xb32[(size_t)n7*64 + lane];
      ACC(base+j+0, v0, 0) ACC(base+j+1, v1, 1) ACC(base+j+2, v2, 2) ACC(base+j+3, v3, 3)
      ACC(base+j+4, v4, 0) ACC(base+j+5, v5, 1) ACC(base+j+6, v6, 2) ACC(base+j+7, v7, 3)
    }
    for (; j + 4 <= cnt; j += 4){
      int n0=__shfl(idx,j+0), n1=__shfl(idx,j+1), n2=__shfl(idx,j+2), n3=__shfl(idx,j+3);
      unsigned v0 = xb32[(size_t)n0*64 + lane];
      unsigned v1 = xb32[(size_t)n1*64 + lane];
      unsigned v2 = xb32[(size_t)n2*64 + lane];
      unsigned v3 = xb32[(size_t)n3*64 + lane];
      ACC(base+j+0, v0, 0) ACC(base+j+1, v1, 1) ACC(base+j+2, v2, 2) ACC(base+j+3, v3, 3)
    }
    if (j + 2 <= cnt){
      int n0=__shfl(idx,j+0), n1=__shfl(idx,j+1);
      unsigned v0 = xb32[(size_t)n0*64 + lane];
      unsigned v1 = xb32[(size_t)n1*64 + lane];
      ACC(base+j+0, v0, 0) ACC(base+j+1, v1, 1)
      j += 2;
    }
    if (j < cnt){
      int n = __shfl(idx, j);
      unsigned v = xb32[(size_t)n*64 + lane];
      ACC(base+j, v, 2)
    }
  }
#undef ACC

  float k1 = 1.f + epsp[0];
  unsigned xw0 = xb32[(size_t)row0*64 + lane];
  unsigned xw1 = xb32[(size_t)(row0+1)*64 + lane];
  float a0x = (a0x0 + a0x1) + (a0x2 + a0x3);
  float a0y = (a0y0 + a0y1) + (a0y2 + a0y3);
  float a1x = (a1x0 + a1x1) + (a1x2 + a1x3);
  float a1y = (a1y0 + a1y1) + (a1y2 + a1y3);
  h0[(size_t)row0*64 + lane]     = pack2(fmaf(k1, blo(xw0), a0x), fmaf(k1, bhi(xw0), a0y));
  h0[(size_t)(row0+1)*64 + lane] = pack2(fmaf(k1, blo(xw1), a1x), fmaf(k1, bhi(xw1), a1y));
}

// Fused MLP, T4 pipeline (R13 schedule) with TWO tiles per wave: 32 output rows/wave,
// 32 MFMA per phase per wave. 16 phases of 16KB slices, quad-buffered, vmcnt(8) steady.
// (no setprio: measured -5us vs with, consistent with m190 on lockstep GEMM schedules)
__global__ __launch_bounds__(256, 2) void k_mlp(const unsigned short* __restrict__ h0,
        const unsigned short* __restrict__ xb16,
        const bf16x8* __restrict__ W1s, const float* __restrict__ b1,
        const bf16x8* __restrict__ W2s, const bf16x8* __restrict__ Wps,
        const float* __restrict__ scale, const float* __restrict__ shift,
        float* __restrict__ out)
{
  __shared__ bf16x8 w[4][1024];                    // 4 x 16KB weight slices
  __shared__ __align__(16) char trans[4][2][1280]; // per-wave 16x(64B+16B pad)
  int tid = threadIdx.x;
  int wv = tid >> 6, lane = tid & 63, g = lane >> 4, r = lane & 15;
  int tA0 = blockIdx.x*8 + wv*2;
  int tB0 = tA0 + 1;
  int tA = min(tA0, NT_ - 1);
  int tB = min(tB0, NT_ - 1);

  const bf16x8* hrowA = (const bf16x8*)(h0 + ((size_t)tA*16 + r)*IND_);
  const bf16x8* hrowB = (const bf16x8*)(h0 + ((size_t)tB*16 + r)*IND_);
  bf16x8 BA[4], BB[4];
  #pragma unroll
  for (int kk = 0; kk < 4; kk++) BA[kk] = hrowA[kk*4 + g];
  #pragma unroll
  for (int kk = 0; kk < 4; kk++) BB[kk] = hrowB[kk*4 + g];

  // 16 slices of 1024 units (16KB): W1 0..3, W2 4..11, Wp 12..15
  const bf16x8* sl[16];
  #pragma unroll
  for (int i = 0; i < 4; i++)  sl[i]      = W1s + i*1024;
  #pragma unroll
  for (int i = 0; i < 8; i++)  sl[4 + i]  = W2s + i*1024;
  #pragma unroll
  for (int i = 0; i < 4; i++)  sl[12 + i] = Wps + i*1024;

  auto STAGE = [&](int buf, const bf16x8* src){
    #pragma unroll
    for (int i = 0; i < 4; i++)
      gload_lds16(&src[i*256 + wv*64 + lane], &w[buf][i*256 + wv*64]);
  };
  f32x4 accA[16], accB[16];
  auto MF16 = [&](int buf, bf16x8 f0, bf16x8 f1, int tb, f32x4 (&acc)[16]){
    #pragma unroll
    for (int tt = 0; tt < 8; tt++)
      acc[tb+tt] = __builtin_amdgcn_mfma_f32_16x16x32_bf16(w[buf][(tt*2+0)*64 + lane], f0, acc[tb+tt], 0,0,0);
    #pragma unroll
    for (int tt = 0; tt < 8; tt++)
      acc[tb+tt] = __builtin_amdgcn_mfma_f32_16x16x32_bf16(w[buf][(tt*2+1)*64 + lane], f1, acc[tb+tt], 0,0,0);
  };
  #pragma unroll
  for (int t = 0; t < 16; t++){ accA[t] = (f32x4){0.f,0.f,0.f,0.f}; accB[t] = (f32x4){0.f,0.f,0.f,0.f}; }

  const float4* b1v = (const float4*)b1;
  auto EPI = [&](f32x4 (&acc)[16], bf16x8 (&H)[8]){
    #pragma unroll
    for (int kkh = 0; kkh < 8; kkh++){
      char* tr = &trans[wv][kkh & 1][0];
      #pragma unroll
      for (int h = 0; h < 2; h++){
        int t = 2*kkh + h;
        float4 bb = b1v[t*4 + g];
        f32x4 a = acc[t];
        float v0 = fmaxf(a.x + bb.x, 0.f);
        float v1 = fmaxf(a.y + bb.y, 0.f);
        float v2 = fmaxf(a.z + bb.z, 0.f);
        float v3 = fmaxf(a.w + bb.w, 0.f);
        u32x2 dd; dd.x = pack2(v0, v1); dd.y = pack2(v2, v3);
        *(u32x2*)(tr + r*80 + h*32 + g*8) = dd;
      }
      H[kkh] = *(const bf16x8*)(tr + r*80 + g*16);
    }
    #pragma unroll
    for (int t = 0; t < 16; t++) acc[t] = (f32x4){0.f,0.f,0.f,0.f};
  };

#define PHASE(P, VM, FA0, FA1, FB0, FB1, TB)                       \
  { if ((P) + 2 < 16) STAGE(((P)+2)&3, sl[(P)+2]);                 \
    asm volatile("s_waitcnt vmcnt(" VM ")" ::: "memory");          \
    __builtin_amdgcn_s_barrier();                                  \
    MF16((P)&3, FA0, FA1, TB, accA);                               \
    MF16((P)&3, FB0, FB1, TB, accB); }

  STAGE(0, sl[0]);
  STAGE(1, sl[1]);

  // W1: h0 @ W1  (phases 0..3)
  PHASE(0,  "8", BA[0], BA[1], BB[0], BB[1], 0)
  PHASE(1,  "8", BA[0], BA[1], BB[0], BB[1], 8)
  PHASE(2,  "8", BA[2], BA[3], BB[2], BB[3], 0)
  PHASE(3,  "8", BA[2], BA[3], BB[2], BB[3], 8)

  // epilogue B (both tiles): bias+relu -> bf16 H-fragments; runs while slices 4,5 stage
  bf16x8 HA[8], HB[8];
  EPI(accA, HA);
  EPI(accB, HB);

  // W2: h1 @ W2  (phases 4..11)
  PHASE(4,  "8", HA[0], HA[1], HB[0], HB[1], 0)
  PHASE(5,  "8", HA[0], HA[1], HB[0], HB[1], 8)
  PHASE(6,  "8", HA[2], HA[3], HB[2], HB[3], 0)
  PHASE(7,  "8", HA[2], HA[3], HB[2], HB[3], 8)
  PHASE(8,  "8", HA[4], HA[5], HB[4], HB[5], 0)
  PHASE(9,  "8", HA[4], HA[5], HB[4], HB[5], 8)

  // x fragments for the Wp phases (loaded late: B regs dead, most of H dead soon)
  const bf16x8* xrowA = (const bf16x8*)(xb16 + ((size_t)tA*16 + r)*IND_);
  const bf16x8* xrowB = (const bf16x8*)(xb16 + ((size_t)tB*16 + r)*IND_);
  bf16x8 XA[4], XB[4];
  #pragma unroll
  for (int kk = 0; kk < 4; kk++) XA[kk] = xrowA[kk*4 + g];
  #pragma unroll
  for (int kk = 0; kk < 4; kk++) XB[kk] = xrowB[kk*4 + g];

  PHASE(10, "8", HA[6], HA[7], HB[6], HB[7], 0)
  PHASE(11, "8", HA[6], HA[7], HB[6], HB[7], 8)
  // Wp: x @ Wp  (phases 12..15)
  PHASE(12, "8", XA[0], XA[1], XB[0], XB[1], 0)
  PHASE(13, "8", XA[0], XA[1], XB[0], XB[1], 8)
  PHASE(14, "4", XA[2], XA[3], XB[2], XB[3], 0)
  PHASE(15, "0", XA[2], XA[3], XB[2], XB[3], 8)
#undef PHASE

  const float4* sc = (const float4*)scale;
  const float4* sh = (const float4*)shift;
  if (tA0 < NT_){
    #pragma unroll
    for (int t = 0; t < 16; t++){
      float4 s = sc[t*4 + g], b = sh[t*4 + g];
      f32x4 a = accA[t];
      float4 o;
      o.x = fmaf(a.x, s.x, b.x);
      o.y = fmaf(a.y, s.y, b.y);
      o.z = fmaf(a.z, s.z, b.z);
      o.w = fmaf(a.w, s.w, b.w);
      *(float4*)(out + ((size_t)tA*16 + r)*OUTD_ + t*16 + g*4) = o;
    }
  }
  if (tB0 < NT_){
    #pragma unroll
    for (int t = 0; t < 16; t++){
      float4 s = sc[t*4 + g], b = sh[t*4 + g];
      f32x4 a = accB[t];
      float4 o;
      o.x = fmaf(a.x, s.x, b.x);
      o.y = fmaf(a.y, s.y, b.y);
      o.z = fmaf(a.z, s.z, b.z);
      o.w = fmaf(a.w, s.w, b.w);
      *(float4*)(out + ((size_t)tB*16 + r)*OUTD_ + t*16 + g*4) = o;
    }
  }
}

extern "C" void kernel_launch(void* const* d_in, const int* in_sizes, int n_in,
                              void* d_out, int out_size, void* d_ws, size_t ws_size,
                              hipStream_t stream)
{
  const float* x     = (const float*)d_in[0];
  const int*   ei    = (const int*)d_in[1];     // [2][E]: src then dst
  const float* eps   = (const float*)d_in[2];
  const float* W1    = (const float*)d_in[3];
  const float* b1    = (const float*)d_in[4];
  const float* W2    = (const float*)d_in[5];
  const float* b2    = (const float*)d_in[6];
  const float* gamma = (const float*)d_in[7];
  const float* beta  = (const float*)d_in[8];
  const float* rmean = (const float*)d_in[9];
  const float* rvar  = (const float*)d_in[10];
  const float* Wp    = (const float*)d_in[11];
  const float* bp    = (const float*)d_in[12];
  float* out = (float*)d_out;

  char* ws = (char*)d_ws; size_t off = 0;
  auto carve = [&](size_t b)->char* { char* p = ws + off; off = (off + b + 255) & ~(size_t)255; return p; };
  unsigned*       xbuf  = (unsigned*)carve((size_t)CASTN_*4);   // x as bf16 pairs
  unsigned*       h0    = (unsigned*)carve((size_t)N_*64*4);    // h0 as bf16 pairs
  unsigned short* W1s   = (unsigned short*)carve(4096*16);
  unsigned short* W2s   = (unsigned short*)carve(8192*16);
  unsigned short* Wps   = (unsigned short*)carve(4096*16);
  float*          scale = (float*)carve(256*4);
  float*          shift = (float*)carve(256*4);
  int*            deg   = (int*)carve((size_t)N_*4);            // deg, cur adjacent: one memset
  int*            cur   = (int*)carve((size_t)N_*4);
  int*            offs  = (int*)carve((size_t)(N_+1)*4);
  int*            adj   = (int*)carve((size_t)E_*4);
  int*            bsum  = (int*)carve((size_t)NB_*4);

  // deg block is padded to 256B; cur follows immediately -> zero both in one node
  size_t degpad = (((size_t)N_*4 + 255) & ~(size_t)255);
  hipMemsetAsync(deg, 0, degpad + (size_t)N_*4, stream);

  k_prep <<<(16640 + CAST4_ + E_ + 255)/256, 256, 0, stream>>>(x, W1, W2, Wp, b2, gamma, beta,
                                  rmean, rvar, bp, ei + E_, deg,
                                  W1s, W2s, Wps, scale, shift, xbuf);
  k_scan1<<<NB_, 1024, 0, stream>>>(deg, bsum, offs);
  k_scan2<<<NB_, 1024, 0, stream>>>(deg, bsum, offs);
  k_fill <<<(E_+255)/256, 256, 0, stream>>>(ei, ei + E_, offs, cur, adj);
  k_agg  <<<(N_/2+3)/4, 256, 0, stream>>>(xbuf, offs, adj, eps, h0);
  k_mlp  <<<(NT_+7)/8, 256, 0, stream>>>((const unsigned short*)h0, (const unsigned short*)xbuf,
                                         (const bf16x8*)W1s, b1, (const bf16x8*)W2s,
                                         (const bf16x8*)Wps, scale, shift, out);
}

// Round 19
// 173.210 us; speedup vs baseline: 1.0696x; 1.0087x over previous
//
#include <hip/hip_runtime.h>

#define N_ 100000
#define E_ 600000
#define IND_ 128
#define OUTD_ 256
#define NT_ (N_/16)        // 6250 row-tiles of 16
#define NB_ 98             // scan blocks of 1024
#define CASTN_ (N_*IND_/2) // 6.4M u32 words of bf16 pairs
#define CAST4_ (CASTN_/2)  // 3.2M float4 -> u32x2 units

typedef __attribute__((ext_vector_type(8))) short bf16x8;
typedef __attribute__((ext_vector_type(4))) float f32x4;
typedef __attribute__((ext_vector_type(2))) unsigned int u32x2;

static __device__ __forceinline__ unsigned f2bf_u(float f){
  union { float f; unsigned u; } v; v.f = f;
  return (v.u + 0x7fffu + ((v.u >> 16) & 1u)) >> 16;   // RNE bf16
}
static __device__ __forceinline__ unsigned pack2(float a, float b){
  return f2bf_u(a) | (f2bf_u(b) << 16);
}
static __device__ __forceinline__ float blo(unsigned u){
  union { unsigned u; float f; } v; v.u = u << 16; return v.f;
}
static __device__ __forceinline__ float bhi(unsigned u){
  union { unsigned u; float f; } v; v.u = u & 0xffff0000u; return v.f;
}
// async global->LDS DMA, 16B per lane per call (wave: 1KB). LDS base must be wave-uniform.
static __device__ __forceinline__ void gload_lds16(const bf16x8* g, bf16x8* l){
  __builtin_amdgcn_global_load_lds((const __attribute__((address_space(1))) void*)g,
                                   (__attribute__((address_space(3))) void*)l, 16, 0, 0);
}

// ---- weight prep (fp32 -> bf16 fragment order) + BN fold + x -> bf16 cast + degree count
__global__ void k_prep(const float* __restrict__ x,
                       const float* __restrict__ W1, const float* __restrict__ W2,
                       const float* __restrict__ Wp, const float* __restrict__ b2,
                       const float* __restrict__ gamma, const float* __restrict__ beta,
                       const float* __restrict__ mean, const float* __restrict__ var,
                       const float* __restrict__ bp,
                       const int* __restrict__ dst, int* __restrict__ deg,
                       unsigned short* __restrict__ W1s, unsigned short* __restrict__ W2s,
                       unsigned short* __restrict__ Wps,
                       float* __restrict__ scale, float* __restrict__ shift,
                       unsigned* __restrict__ xbw)
{
  int gid = blockIdx.x*256 + threadIdx.x;
  if (gid < 16384) {
    const float* W; unsigned short* Ws; int u;
    if (gid < 4096)       { W = W1; Ws = W1s; u = gid; }
    else if (gid < 12288) { W = W2; Ws = W2s; u = gid - 4096; }
    else                  { W = Wp; Ws = Wps; u = gid - 12288; }
    int l  = u & 63;
    int km = (u >> 6) & 1;
    int t  = (u >> 7) & 15;
    int q  = u >> 11;
    int kk = 2*q + km;
    int kb = kk*32 + (l >> 4)*8;
    int c  = 16*t + (l & 15);
    #pragma unroll
    for (int j = 0; j < 8; j++)
      Ws[u*8 + j] = (unsigned short)f2bf_u(W[(size_t)(kb + j)*OUTD_ + c]);
  } else if (gid < 16640) {
    int c = gid - 16384;
    float s = gamma[c] * rsqrtf(var[c] + 1e-5f);
    scale[c] = s;
    shift[c] = (b2[c] - mean[c]) * s + beta[c] + bp[c];
  } else if (gid < 16640 + CAST4_) {
    int ci = gid - 16640;
    float4 v = ((const float4*)x)[ci];
    u32x2 o; o.x = pack2(v.x, v.y); o.y = pack2(v.z, v.w);
    ((u32x2*)xbw)[ci] = o;
  } else if (gid < 16640 + CAST4_ + E_) {
    int e = gid - 16640 - CAST4_;
    atomicAdd(&deg[dst[e]], 1);
  }
}

// hierarchical scan pass 1: per-1024-chunk sums (parallel, coalesced)
__global__ __launch_bounds__(1024) void k_scan1(const int* __restrict__ deg,
                                                int* __restrict__ bsum, int* __restrict__ offs){
  __shared__ int red[16];
  int tid = threadIdx.x;
  int i = blockIdx.x*1024 + tid;
  int v = (i < N_) ? deg[i] : 0;
  #pragma unroll
  for (int d = 32; d; d >>= 1) v += __shfl_down(v, d);
  if ((tid & 63) == 0) red[tid >> 6] = v;
  __syncthreads();
  if (tid < 16) {
    int s = red[tid];
    #pragma unroll
    for (int d = 8; d; d >>= 1) s += __shfl_down(s, d, 16);
    if (tid == 0) bsum[blockIdx.x] = s;
  }
  if (blockIdx.x == 0 && tid == 0) offs[N_] = E_;
}

// pass 2: each block redundantly scans the 98 block sums + its own chunk
__global__ __launch_bounds__(1024) void k_scan2(const int* __restrict__ deg,
                                                const int* __restrict__ bsum, int* __restrict__ offs){
  __shared__ int bs[128];
  __shared__ int d1[1024];
  int tid = threadIdx.x;
  if (tid < 128) bs[tid] = (tid < NB_) ? bsum[tid] : 0;
  __syncthreads();
  #pragma unroll
  for (int d = 1; d < 128; d <<= 1){
    int v = (tid < 128 && tid >= d) ? bs[tid - d] : 0;
    __syncthreads();
    if (tid < 128) bs[tid] += v;
    __syncthreads();
  }
  int bprefix = (blockIdx.x > 0) ? bs[blockIdx.x - 1] : 0;
  int i = blockIdx.x*1024 + tid;
  int v = (i < N_) ? deg[i] : 0;
  d1[tid] = v;
  __syncthreads();
  #pragma unroll
  for (int d = 1; d < 1024; d <<= 1){
    int t = (tid >= d) ? d1[tid - d] : 0;
    __syncthreads();
    d1[tid] += t;
    __syncthreads();
  }
  if (i < N_) offs[i] = bprefix + d1[tid] - v;
}

__global__ void k_fill(const int* __restrict__ src, const int* __restrict__ dst,
                       const int* __restrict__ offs, int* __restrict__ cur, int* __restrict__ adj){
  int e = blockIdx.x*256 + threadIdx.x;
  if (e < E_) {
    int d = dst[e];
    int p = atomicAdd(&cur[d], 1);
    adj[offs[d] + p] = src[e];
  }
}

// one wave per TWO adjacent dst rows (contiguous CSR range, avg 12 edges): flat graded
// unroll 8/4/2/1 over the combined list; per-element row assignment is wave-uniform.
__global__ void k_agg(const unsigned* __restrict__ xb32, const int* __restrict__ offs,
                      const int* __restrict__ adj, const float* __restrict__ epsp,
                      unsigned* __restrict__ h0)
{
  int pair = blockIdx.x*4 + (threadIdx.x >> 6);
  int lane = threadIdx.x & 63;
  int row0 = pair*2;
  if (row0 >= N_) return;
  int b0 = offs[row0], e0 = offs[row0+1], e1 = offs[row0+2];
  int d0 = e0 - b0;
  int total = e1 - b0;
  float a0x0=0,a0y0=0,a0x1=0,a0y1=0,a0x2=0,a0y2=0,a0x3=0,a0y3=0;
  float a1x0=0,a1y0=0,a1x1=0,a1y1=0,a1x2=0,a1y2=0,a1x3=0,a1y3=0;

#define ACC(P, V, S)                                                        \
  { if ((P) < d0) { a0x##S += blo(V); a0y##S += bhi(V); }                   \
    else          { a1x##S += blo(V); a1y##S += bhi(V); } }

  for (int base = 0; base < total; base += 64){
    int cnt = min(64, total - base);
    int idx = adj[b0 + base + min(lane, cnt - 1)];
    int j = 0;
    for (; j + 8 <= cnt; j += 8){
      int n0=__shfl(idx,j+0), n1=__shfl(idx,j+1), n2=__shfl(idx,j+2), n3=__shfl(idx,j+3);
      int n4=__shfl(idx,j+4), n5=__shfl(idx,j+5), n6=__shfl(idx,j+6), n7=__shfl(idx,j+7);
      unsigned v0 = xb32[(size_t)n0*64 + lane];
      unsigned v1 = xb32[(size_t)n1*64 + lane];
      unsigned v2 = xb32[(size_t)n2*64 + lane];
      unsigned v3 = xb32[(size_t)n3*64 + lane];
      unsigned v4 = xb32[(size_t)n4*64 + lane];
      unsigned v5 = xb32[(size_t)n5*64 + lane];
      unsigned v6 = xb32[(size_t)n6*64 + lane];
      unsigned v7 = xb32[(size_t)n7*64 + lane];
      ACC(base+j+0, v0, 0) ACC(base+j+1, v1, 1) ACC(base+j+2, v2, 2) ACC(base+j+3, v3, 3)
      ACC(base+j+4, v4, 0) ACC(base+j+5, v5, 1) ACC(base+j+6, v6, 2) ACC(base+j+7, v7, 3)
    }
    for (; j + 4 <= cnt; j += 4){
      int n0=__shfl(idx,j+0), n1=__shfl(idx,j+1), n2=__shfl(idx,j+2), n3=__shfl(idx,j+3);
      unsigned v0 = xb32[(size_t)n0*64 + lane];
      unsigned v1 = xb32[(size_t)n1*64 + lane];
      unsigned v2 = xb32[(size_t)n2*64 + lane];
      unsigned v3 = xb32[(size_t)n3*64 + lane];
      ACC(base+j+0, v0, 0) ACC(base+j+1, v1, 1) ACC(base+j+2, v2, 2) ACC(base+j+3, v3, 3)
    }
    if (j + 2 <= cnt){
      int n0=__shfl(idx,j+0), n1=__shfl(idx,j+1);
      unsigned v0 = xb32[(size_t)n0*64 + lane];
      unsigned v1 = xb32[(size_t)n1*64 + lane];
      ACC(base+j+0, v0, 0) ACC(base+j+1, v1, 1)
      j += 2;
    }
    if (j < cnt){
      int n = __shfl(idx, j);
      unsigned v = xb32[(size_t)n*64 + lane];
      ACC(base+j, v, 2)
    }
  }
#undef ACC

  float k1 = 1.f + epsp[0];
  unsigned xw0 = xb32[(size_t)row0*64 + lane];
  unsigned xw1 = xb32[(size_t)(row0+1)*64 + lane];
  float a0x = (a0x0 + a0x1) + (a0x2 + a0x3);
  float a0y = (a0y0 + a0y1) + (a0y2 + a0y3);
  float a1x = (a1x0 + a1x1) + (a1x2 + a1x3);
  float a1y = (a1y0 + a1y1) + (a1y2 + a1y3);
  h0[(size_t)row0*64 + lane]     = pack2(fmaf(k1, blo(xw0), a0x), fmaf(k1, bhi(xw0), a0y));
  h0[(size_t)(row0+1)*64 + lane] = pack2(fmaf(k1, blo(xw1), a1x), fmaf(k1, bhi(xw1), a1y));
}

// Fused MLP, 2 tiles/wave, 16 phases of 16KB slices, TRIPLE-buffered (48KB w + 5KB trans
// = 54.3KB LDS -> 3 blocks/CU = 12 waves/CU). STAGE(p+2) issued AFTER barrier(p): it
// overwrites buf (p-1)%3 whose readers (MF(p-1)) completed before barrier(p). vmcnt(4)
// steady state (stage p+1 in flight), vmcnt(0) tail.
__global__ __launch_bounds__(256, 2) void k_mlp(const unsigned short* __restrict__ h0,
        const unsigned short* __restrict__ xb16,
        const bf16x8* __restrict__ W1s, const float* __restrict__ b1,
        const bf16x8* __restrict__ W2s, const bf16x8* __restrict__ Wps,
        const float* __restrict__ scale, const float* __restrict__ shift,
        float* __restrict__ out)
{
  __shared__ bf16x8 w[3][1024];                 // 3 x 16KB weight slices
  __shared__ __align__(16) char trans[4][1280]; // per-wave 16x(64B+16B pad)
  int tid = threadIdx.x;
  int wv = tid >> 6, lane = tid & 63, g = lane >> 4, r = lane & 15;
  int tA0 = blockIdx.x*8 + wv*2;
  int tB0 = tA0 + 1;
  int tA = min(tA0, NT_ - 1);
  int tB = min(tB0, NT_ - 1);

  const bf16x8* hrowA = (const bf16x8*)(h0 + ((size_t)tA*16 + r)*IND_);
  const bf16x8* hrowB = (const bf16x8*)(h0 + ((size_t)tB*16 + r)*IND_);
  bf16x8 BA[4], BB[4];
  #pragma unroll
  for (int kk = 0; kk < 4; kk++) BA[kk] = hrowA[kk*4 + g];
  #pragma unroll
  for (int kk = 0; kk < 4; kk++) BB[kk] = hrowB[kk*4 + g];

  // 16 slices of 1024 units (16KB): W1 0..3, W2 4..11, Wp 12..15
  const bf16x8* sl[16];
  #pragma unroll
  for (int i = 0; i < 4; i++)  sl[i]      = W1s + i*1024;
  #pragma unroll
  for (int i = 0; i < 8; i++)  sl[4 + i]  = W2s + i*1024;
  #pragma unroll
  for (int i = 0; i < 4; i++)  sl[12 + i] = Wps + i*1024;

  auto STAGE = [&](int buf, const bf16x8* src){
    #pragma unroll
    for (int i = 0; i < 4; i++)
      gload_lds16(&src[i*256 + wv*64 + lane], &w[buf][i*256 + wv*64]);
  };
  f32x4 accA[16], accB[16];
  auto MF16 = [&](int buf, bf16x8 f0, bf16x8 f1, int tb, f32x4 (&acc)[16]){
    #pragma unroll
    for (int tt = 0; tt < 8; tt++)
      acc[tb+tt] = __builtin_amdgcn_mfma_f32_16x16x32_bf16(w[buf][(tt*2+0)*64 + lane], f0, acc[tb+tt], 0,0,0);
    #pragma unroll
    for (int tt = 0; tt < 8; tt++)
      acc[tb+tt] = __builtin_amdgcn_mfma_f32_16x16x32_bf16(w[buf][(tt*2+1)*64 + lane], f1, acc[tb+tt], 0,0,0);
  };
  #pragma unroll
  for (int t = 0; t < 16; t++){ accA[t] = (f32x4){0.f,0.f,0.f,0.f}; accB[t] = (f32x4){0.f,0.f,0.f,0.f}; }

  const float4* b1v = (const float4*)b1;
  auto EPI = [&](f32x4 (&acc)[16], bf16x8 (&H)[8]){
    #pragma unroll
    for (int kkh = 0; kkh < 8; kkh++){
      char* tr = &trans[wv][0];
      #pragma unroll
      for (int h = 0; h < 2; h++){
        int t = 2*kkh + h;
        float4 bb = b1v[t*4 + g];
        f32x4 a = acc[t];
        float v0 = fmaxf(a.x + bb.x, 0.f);
        float v1 = fmaxf(a.y + bb.y, 0.f);
        float v2 = fmaxf(a.z + bb.z, 0.f);
        float v3 = fmaxf(a.w + bb.w, 0.f);
        u32x2 dd; dd.x = pack2(v0, v1); dd.y = pack2(v2, v3);
        *(u32x2*)(tr + r*80 + h*32 + g*8) = dd;
      }
      H[kkh] = *(const bf16x8*)(tr + r*80 + g*16);
    }
    #pragma unroll
    for (int t = 0; t < 16; t++) acc[t] = (f32x4){0.f,0.f,0.f,0.f};
  };

// 3-buffer: buf = P % 3. STAGE(P+2) after barrier(P) overwrites (P+2)%3 = (P-1)%3,
// safe because MF(P-1) finished before barrier(P).
#define PHASE(P, VM, FA0, FA1, FB0, FB1, TB)                       \
  { asm volatile("s_waitcnt vmcnt(" VM ")" ::: "memory");          \
    __builtin_amdgcn_s_barrier();                                  \
    if ((P) + 2 < 16) STAGE(((P)+2)%3, sl[(P)+2]);                 \
    MF16((P)%3, FA0, FA1, TB, accA);                               \
    MF16((P)%3, FB0, FB1, TB, accB); }

  STAGE(0, sl[0]);
  STAGE(1, sl[1]);

  // W1: h0 @ W1  (phases 0..3)
  PHASE(0,  "4", BA[0], BA[1], BB[0], BB[1], 0)
  PHASE(1,  "4", BA[0], BA[1], BB[0], BB[1], 8)
  PHASE(2,  "4", BA[2], BA[3], BB[2], BB[3], 0)
  PHASE(3,  "4", BA[2], BA[3], BB[2], BB[3], 8)

  // epilogue B (both tiles): bias+relu -> bf16 H-fragments; runs while slices 4,5 stage
  bf16x8 HA[8], HB[8];
  EPI(accA, HA);
  EPI(accB, HB);

  // W2: h1 @ W2  (phases 4..11)
  PHASE(4,  "4", HA[0], HA[1], HB[0], HB[1], 0)
  PHASE(5,  "4", HA[0], HA[1], HB[0], HB[1], 8)
  PHASE(6,  "4", HA[2], HA[3], HB[2], HB[3], 0)
  PHASE(7,  "4", HA[2], HA[3], HB[2], HB[3], 8)
  PHASE(8,  "4", HA[4], HA[5], HB[4], HB[5], 0)
  PHASE(9,  "4", HA[4], HA[5], HB[4], HB[5], 8)

  // x fragments for the Wp phases (loaded late: B regs dead, most of H dead soon)
  const bf16x8* xrowA = (const bf16x8*)(xb16 + ((size_t)tA*16 + r)*IND_);
  const bf16x8* xrowB = (const bf16x8*)(xb16 + ((size_t)tB*16 + r)*IND_);
  bf16x8 XA[4], XB[4];
  #pragma unroll
  for (int kk = 0; kk < 4; kk++) XA[kk] = xrowA[kk*4 + g];
  #pragma unroll
  for (int kk = 0; kk < 4; kk++) XB[kk] = xrowB[kk*4 + g];

  PHASE(10, "4", HA[6], HA[7], HB[6], HB[7], 0)
  PHASE(11, "4", HA[6], HA[7], HB[6], HB[7], 8)
  // Wp: x @ Wp  (phases 12..15)
  PHASE(12, "4", XA[0], XA[1], XB[0], XB[1], 0)
  PHASE(13, "4", XA[0], XA[1], XB[0], XB[1], 8)
  PHASE(14, "4", XA[2], XA[3], XB[2], XB[3], 0)
  PHASE(15, "0", XA[2], XA[3], XB[2], XB[3], 8)
#undef PHASE

  const float4* sc = (const float4*)scale;
  const float4* sh = (const float4*)shift;
  if (tA0 < NT_){
    #pragma unroll
    for (int t = 0; t < 16; t++){
      float4 s = sc[t*4 + g], b = sh[t*4 + g];
      f32x4 a = accA[t];
      float4 o;
      o.x = fmaf(a.x, s.x, b.x);
      o.y = fmaf(a.y, s.y, b.y);
      o.z = fmaf(a.z, s.z, b.z);
      o.w = fmaf(a.w, s.w, b.w);
      *(float4*)(out + ((size_t)tA*16 + r)*OUTD_ + t*16 + g*4) = o;
    }
  }
  if (tB0 < NT_){
    #pragma unroll
    for (int t = 0; t < 16; t++){
      float4 s = sc[t*4 + g], b = sh[t*4 + g];
      f32x4 a = accB[t];
      float4 o;
      o.x = fmaf(a.x, s.x, b.x);
      o.y = fmaf(a.y, s.y, b.y);
      o.z = fmaf(a.z, s.z, b.z);
      o.w = fmaf(a.w, s.w, b.w);
      *(float4*)(out + ((size_t)tB*16 + r)*OUTD_ + t*16 + g*4) = o;
    }
  }
}

extern "C" void kernel_launch(void* const* d_in, const int* in_sizes, int n_in,
                              void* d_out, int out_size, void* d_ws, size_t ws_size,
                              hipStream_t stream)
{
  const float* x     = (const float*)d_in[0];
  const int*   ei    = (const int*)d_in[1];     // [2][E]: src then dst
  const float* eps   = (const float*)d_in[2];
  const float* W1    = (const float*)d_in[3];
  const float* b1    = (const float*)d_in[4];
  const float* W2    = (const float*)d_in[5];
  const float* b2    = (const float*)d_in[6];
  const float* gamma = (const float*)d_in[7];
  const float* beta  = (const float*)d_in[8];
  const float* rmean = (const float*)d_in[9];
  const float* rvar  = (const float*)d_in[10];
  const float* Wp    = (const float*)d_in[11];
  const float* bp    = (const float*)d_in[12];
  float* out = (float*)d_out;

  char* ws = (char*)d_ws; size_t off = 0;
  auto carve = [&](size_t b)->char* { char* p = ws + off; off = (off + b + 255) & ~(size_t)255; return p; };
  unsigned*       xbuf  = (unsigned*)carve((size_t)CASTN_*4);   // x as bf16 pairs
  unsigned*       h0    = (unsigned*)carve((size_t)N_*64*4);    // h0 as bf16 pairs
  unsigned short* W1s   = (unsigned short*)carve(4096*16);
  unsigned short* W2s   = (unsigned short*)carve(8192*16);
  unsigned short* Wps   = (unsigned short*)carve(4096*16);
  float*          scale = (float*)carve(256*4);
  float*          shift = (float*)carve(256*4);
  int*            deg   = (int*)carve((size_t)N_*4);            // deg, cur adjacent: one memset
  int*            cur   = (int*)carve((size_t)N_*4);
  int*            offs  = (int*)carve((size_t)(N_+1)*4);
  int*            adj   = (int*)carve((size_t)E_*4);
  int*            bsum  = (int*)carve((size_t)NB_*4);

  // deg block is padded to 256B; cur follows immediately -> zero both in one node
  size_t degpad = (((size_t)N_*4 + 255) & ~(size_t)255);
  hipMemsetAsync(deg, 0, degpad + (size_t)N_*4, stream);

  k_prep <<<(16640 + CAST4_ + E_ + 255)/256, 256, 0, stream>>>(x, W1, W2, Wp, b2, gamma, beta,
                                  rmean, rvar, bp, ei + E_, deg,
                                  W1s, W2s, Wps, scale, shift, xbuf);
  k_scan1<<<NB_, 1024, 0, stream>>>(deg, bsum, offs);
  k_scan2<<<NB_, 1024, 0, stream>>>(deg, bsum, offs);
  k_fill <<<(E_+255)/256, 256, 0, stream>>>(ei, ei + E_, offs, cur, adj);
  k_agg  <<<(N_/2+3)/4, 256, 0, stream>>>(xbuf, offs, adj, eps, h0);
  k_mlp  <<<(NT_+7)/8, 256, 0, stream>>>((const unsigned short*)h0, (const unsigned short*)xbuf,
                                         (const bf16x8*)W1s, b1, (const bf16x8*)W2s,
                                         (const bf16x8*)Wps, scale, shift, out);
}